// Round 10
// baseline (378.732 us; speedup 1.0000x reference)
//
#include <hip/hip_runtime.h>
#include <hip/hip_bf16.h>
#include <type_traits>

typedef __attribute__((ext_vector_type(8))) short short8;
typedef __attribute__((ext_vector_type(4))) short s16x4;
typedef __attribute__((ext_vector_type(4))) float f32x4;
typedef unsigned short u16;
typedef unsigned int   u32;
typedef unsigned long long u64;

// B=4, S=2048, D=1024, H=16, DK=64, M = B*S = 8192

#if __has_builtin(__builtin_amdgcn_mfma_f32_16x16x16bf16_1k)
#define MFMA16(a, b, c) __builtin_amdgcn_mfma_f32_16x16x16bf16_1k(a, b, c, 0, 0, 0)
#define HAVE_MFMA16 1
#elif __has_builtin(__builtin_amdgcn_mfma_f32_16x16x16_bf16)
#define MFMA16(a, b, c) __builtin_amdgcn_mfma_f32_16x16x16_bf16(a, b, c, 0, 0, 0)
#define HAVE_MFMA16 1
#else
#define HAVE_MFMA16 0
#endif

static __device__ __forceinline__ u16 f2b(float f) {
  u32 u = __builtin_bit_cast(u32, f);
  u = (u + 0x7fffu + ((u >> 16) & 1u)) >> 16;
  return (u16)u;
}
static __device__ __forceinline__ float b2f(u16 h) {
  return __builtin_bit_cast(float, ((u32)h) << 16);
}
static __device__ __forceinline__ u32 pkbf(float a, float b) {
  // v_cvt_pk_bf16_f32; union pun (bit_cast rejects non-trivially-copyable)
  union { __hip_bfloat162 t; u32 u; } c;
  c.t = __float22bfloat162_rn(make_float2(a, b));
  return c.u;
}

typedef __attribute__((address_space(1))) const unsigned int gas_u32;
typedef __attribute__((address_space(3))) unsigned int las_u32;
static __device__ __forceinline__ void glds16(const u16* g, u16* l) {
  __builtin_amdgcn_global_load_lds((gas_u32*)g, (las_u32*)l, 16, 0, 0);
}

// ---------------- fused fp32 -> bf16 convert (x + 4 weights) ----------------
__global__ __launch_bounds__(256) void cvt_all(
    const float* __restrict__ x, const float* __restrict__ wq,
    const float* __restrict__ wk, const float* __restrict__ wv,
    const float* __restrict__ wo, u16* __restrict__ xb, u16* __restrict__ wqb,
    u16* __restrict__ wkb, u16* __restrict__ wvb, u16* __restrict__ wob) {
  int u = blockIdx.x * 256 + threadIdx.x;  // unit of 4 floats
  if (u >= 3145728) return;
  const float* src; u16* dst; int off;
  if (u < 2097152) { src = x; dst = xb; off = u; }
  else {
    int t = u - 2097152;
    int w = t >> 18;
    off = t & 0x3FFFF;
    src = (w == 0) ? wq : (w == 1) ? wk : (w == 2) ? wv : wo;
    dst = (w == 0) ? wqb : (w == 1) ? wkb : (w == 2) ? wvb : wob;
  }
  int i = off * 4;
  float4 v = *(const float4*)(src + i);
  union { u16 us[4]; u64 ull; } o;
  o.us[0] = f2b(v.x); o.us[1] = f2b(v.y); o.us[2] = f2b(v.z); o.us[3] = f2b(v.w);
  *(u64*)(dst + i) = o.ull;
}

// ---------------- GEMM: C[m,n] = sum_k A[m,k]*B[n,k]  (B^T form) ----------
// TM: 0 = f32 row-major, 2 = bf16 transposed-to-Vt (fused V transpose),
//     3 = bf16 row-major with FUSED RoPE (pairs (2i,2i+1) live in adjacent
//         lanes cc,cc^1 -> one shfl_xor(1) + __sinf/__cosf per element; rsc
//         is the post-rotation scale: Q gets 0.125*log2e, K gets 1.0).
//         NOTE: __sinf/__cosf, NOT sincosf — the pointer-based OCML sincos
//         fails mem2reg in the unrolled epilogue and generated 1.9 GB of
//         scratch writes (R8: gemm_qkv 444us, WRITE_SIZE 1.93GB, VGPR 76).
template <typename OT, int TM>
static __device__ __forceinline__ void gemm_body(const u16* __restrict__ A,
                                                 const u16* __restrict__ B,
                                                 OT* __restrict__ C,
                                                 int m0, int n0,
                                                 const int* __restrict__ pos,
                                                 float rsc) {
  __shared__ u16 As[4096];
  __shared__ u16 Bs[4096];

  const int tid  = threadIdx.x;
  const int lane = tid & 63;
  const int wv   = tid >> 6;
  const int quad = lane >> 4;
  const int cc   = lane & 15;
  const int wr   = wv >> 1;
  const int wc   = wv & 1;

  f32x4 acc[4][4];
#pragma unroll
  for (int i = 0; i < 4; i++)
#pragma unroll
    for (int j = 0; j < 4; j++) acc[i][j] = (f32x4){0.f, 0.f, 0.f, 0.f};

  const int p0 = wv * 128 + lane;
  const int p1 = p0 + 64;
  const int r0 = p0 >> 2, g0 = (p0 & 3) ^ (r0 & 3);
  const int r1 = p1 >> 2, g1 = (p1 & 3) ^ (r1 & 3);
  const u16* gA0 = A + (size_t)(m0 + r0) * 1024 + g0 * 8;
  const u16* gA1 = A + (size_t)(m0 + r1) * 1024 + g1 * 8;
  const u16* gB0 = B + (size_t)(n0 + r0) * 1024 + g0 * 8;
  const u16* gB1 = B + (size_t)(n0 + r1) * 1024 + g1 * 8;
  u16* lA = As + wv * 1024;
  u16* lB = Bs + wv * 1024;

  for (int k0 = 0; k0 < 1024; k0 += 32) {
    __syncthreads();
    glds16(gA0 + k0, lA);
    glds16(gA1 + k0, lA + 512);
    glds16(gB0 + k0, lB);
    glds16(gB1 + k0, lB + 512);
    __syncthreads();

    short8 af[4], bf[4];
#pragma unroll
    for (int mt = 0; mt < 4; mt++) {
      int ra = wr * 64 + mt * 16 + cc;
      af[mt] = *(const short8*)&As[ra * 32 + ((quad ^ (ra & 3)) * 8)];
    }
#pragma unroll
    for (int nt = 0; nt < 4; nt++) {
      int rb = wc * 64 + nt * 16 + cc;
      bf[nt] = *(const short8*)&Bs[rb * 32 + ((quad ^ (rb & 3)) * 8)];
    }
#pragma unroll
    for (int mt = 0; mt < 4; mt++)
#pragma unroll
      for (int nt = 0; nt < 4; nt++)
        acc[mt][nt] = __builtin_amdgcn_mfma_f32_16x16x32_bf16(af[mt], bf[nt], acc[mt][nt], 0, 0, 0);
  }

  if constexpr (TM == 3) {
    // fused RoPE epilogue (scratch-free trig)
    float prow[4][4];  // token position per (mt, r)
#pragma unroll
    for (int mt = 0; mt < 4; mt++)
#pragma unroll
      for (int r = 0; r < 4; r++)
        prow[mt][r] = (float)pos[(m0 + wr * 64 + mt * 16 + quad * 4 + r) & 2047];
#pragma unroll
    for (int mt = 0; mt < 4; mt++)
#pragma unroll
      for (int nt = 0; nt < 4; nt++) {
        const int col = n0 + wc * 64 + nt * 16 + cc;
        const int fi  = (col & 63) >> 1;
        const float inv = exp2f(-(float)fi * 0.41524101186092033f);
        const bool odd = col & 1;
#pragma unroll
        for (int r = 0; r < 4; r++) {
          const int row = m0 + wr * 64 + mt * 16 + quad * 4 + r;
          const float ang = prow[mt][r] * inv;
          const float sn = __sinf(ang);
          const float cs = __cosf(ang);
          const float x = acc[mt][nt][r];
          const float p = __shfl_xor(x, 1);
          const float y = odd ? (p * sn + x * cs) : (x * cs - p * sn);
          C[(size_t)row * 1024 + col] = f2b(y * rsc);
        }
      }
  } else {
#pragma unroll
    for (int mt = 0; mt < 4; mt++)
#pragma unroll
      for (int nt = 0; nt < 4; nt++) {
        if constexpr (TM == 2) {
          const int col = n0 + wc * 64 + nt * 16 + cc;
          const int rowbase = m0 + wr * 64 + mt * 16 + quad * 4;
          const int bsel = rowbase >> 11;
          const int s0 = rowbase & 2047;
          union { u16 us[4]; u64 ull; } o;
#pragma unroll
          for (int r = 0; r < 4; r++) o.us[r] = f2b(acc[mt][nt][r]);
          *(u64*)&C[((size_t)(bsel * 1024 + col)) * 2048 + s0] = o.ull;
        } else {
#pragma unroll
          for (int r = 0; r < 4; r++) {
            int row = m0 + wr * 64 + mt * 16 + quad * 4 + r;
            int col = n0 + wc * 64 + nt * 16 + cc;
            C[(size_t)row * 1024 + col] = acc[mt][nt][r];
          }
        }
      }
  }
}

// linear grid 1536, XCD-swizzled: each XCD gets 8 contiguous m-panels with
// all their (sel, n0) blocks -> A-panel reuse stays in one XCD's L2.
__global__ __launch_bounds__(256) void gemm_qkv(const u16* __restrict__ A,
                                                const u16* __restrict__ Bq,
                                                const u16* __restrict__ Bk,
                                                const u16* __restrict__ Bv,
                                                u16* __restrict__ Q,
                                                u16* __restrict__ K,
                                                u16* __restrict__ Vt,
                                                const int* __restrict__ pos) {
  const int lin = blockIdx.x;
  const int swz = (lin & 7) * 192 + (lin >> 3);
  const int m0  = (swz / 24) * 128;
  const int rem = swz % 24;
  const int sel = rem >> 3;
  const int n0  = (rem & 7) * 128;
  if (sel == 0)      gemm_body<u16, 3>(A, Bq, Q,  m0, n0, pos, 0.18033688011112042f);
  else if (sel == 1) gemm_body<u16, 3>(A, Bk, K,  m0, n0, pos, 1.0f);
  else               gemm_body<u16, 2>(A, Bv, Vt, m0, n0, nullptr, 0.f);
}

__global__ __launch_bounds__(256) void gemm_out(const u16* __restrict__ A,
                                                const u16* __restrict__ B,
                                                float* __restrict__ C) {
  const int lin = blockIdx.x;
  const int swz = (lin & 7) * 64 + (lin >> 3);
  gemm_body<float, 0>(A, B, C, (swz >> 3) * 128, (swz & 7) * 128, nullptr, 0.f);
}

// ---------------- causal flash attention V11 (8-wave, QBLK=256) ----------
// 8 waves/block, 256 q-rows/block, grid 512 = exactly 2 blocks/CU (zero
// drain tail; 16 waves/CU vs V9's 12). Per-wave work identical to V9 (32 q
// rows, same fragments/registers); 8 waves share each staged 128-key K/V
// tile (per-wave staging and K/V HBM reads halve). (512,4) caps 128 unified
// regs; kk-outer body ≈ 116 -> no spill expected (WRITE_SIZE verifies).
// Waves 0-3 own rows q0..q0+127 (diag tile 2qt), waves 4-7 own q0+128..+255
// (diag 2qt+1); wave-uniform skip of fully-masked tiles. ALL barriers
// unconditional at uniform program points. Block decode groups 8 bh per
// XCD (lin&7 = bh>>3) for K/V L2 reuse.

#define S_STEP(MT, SV)                                                     \
  do {                                                                     \
    __builtin_amdgcn_s_setprio(1);                                         \
    _Pragma("unroll")                                                      \
    for (int nt = 0; nt < 8; ++nt) {                                       \
      const int rbase = (nt * 16 + cc) * 64;                               \
      short8 bk0 = *(const short8*)&Ks[cur][rbase + pk0];                  \
      short8 bk1 = *(const short8*)&Ks[cur][rbase + (pk0 ^ 32)];           \
      f32x4 z = (f32x4){0.f, 0.f, 0.f, 0.f};                               \
      z = __builtin_amdgcn_mfma_f32_16x16x32_bf16(bk0, qf[MT][0], z, 0, 0, 0); \
      SV[nt] = __builtin_amdgcn_mfma_f32_16x16x32_bf16(bk1, qf[MT][1], z, 0, 0, 0); \
    }                                                                      \
    __builtin_amdgcn_s_setprio(0);                                         \
  } while (0)

#define MASK_STEP(MT, SV)                                                  \
  do {                                                                     \
    const int qg = q0 + wv * 32 + MT * 16 + cc;                            \
    const int kb = kt * 128 + quad * 4;                                    \
    _Pragma("unroll")                                                      \
    for (int nt = 0; nt < 8; ++nt)                                         \
      _Pragma("unroll")                                                    \
      for (int r = 0; r < 4; ++r)                                          \
        if (kb + nt * 16 + r > qg) SV[nt][r] = -3.0e38f;                   \
  } while (0)

// max-reduce + deferred rescale (T13): skip o_acc rescale while the new
// tile max stays within 2^11 of the running max.
#define MAXRED_STEP(MT, SV)                                                \
  do {                                                                     \
    float mx = fmaxf(fmaxf(SV[0][0], SV[0][1]), fmaxf(SV[0][2], SV[0][3]));\
    _Pragma("unroll")                                                      \
    for (int nt = 1; nt < 8; ++nt)                                         \
      mx = fmaxf(mx, fmaxf(fmaxf(SV[nt][0], SV[nt][1]),                    \
                           fmaxf(SV[nt][2], SV[nt][3])));                  \
    mx = fmaxf(mx, __shfl_xor(mx, 16));                                    \
    mx = fmaxf(mx, __shfl_xor(mx, 32));                                    \
    if (!__all(mx <= m_i[MT] + 11.0f)) {                                   \
      const float mn = fmaxf(m_i[MT], mx);                                 \
      const float al = exp2f(m_i[MT] - mn);                                \
      m_i[MT] = mn;                                                        \
      l_i[MT] *= al;                                                       \
      f32x4 al4;                                                           \
      _Pragma("unroll")                                                    \
      for (int r = 0; r < 4; ++r) al4[r] = __shfl(al, quad * 4 + r);       \
      _Pragma("unroll")                                                    \
      for (int nt = 0; nt < 4; ++nt) o_acc[MT][nt] *= al4;                 \
    }                                                                      \
  } while (0)

#if HAVE_MFMA16
// fused exp2 -> pack -> PV, kk-outer: one P fragment live at a time
#define EXPPV_STEP(MT, SV)                                                 \
  do {                                                                     \
    const float mu = m_i[MT];                                              \
    float ps = 0.f;                                                        \
    __builtin_amdgcn_s_setprio(1);                                         \
    _Pragma("unroll")                                                      \
    for (int kk = 0; kk < 8; ++kk) {                                       \
      float e0 = exp2f(SV[kk][0] - mu);                                    \
      float e1 = exp2f(SV[kk][1] - mu);                                    \
      float e2 = exp2f(SV[kk][2] - mu);                                    \
      float e3 = exp2f(SV[kk][3] - mu);                                    \
      ps += (e0 + e1) + (e2 + e3);                                         \
      union { u32 w[2]; s16x4 v; } pu;                                     \
      pu.w[0] = pkbf(e0, e1);                                              \
      pu.w[1] = pkbf(e2, e3);                                              \
      const int pos = (kk * 2 + (quad >> 1) + cc) & 15;                    \
      _Pragma("unroll")                                                    \
      for (int nt = 0; nt < 4; ++nt) {                                     \
        s16x4 bv = *(const s16x4*)&Vs[(nt * 16 + cc) * 128 + pos * 8 + (quad & 1) * 4]; \
        o_acc[MT][nt] = MFMA16(pu.v, bv, o_acc[MT][nt]);                   \
      }                                                                    \
    }                                                                      \
    __builtin_amdgcn_s_setprio(0);                                         \
    l_i[MT] += ps;                                                         \
  } while (0)
#else
// fallback: exp all, stage P through LDS to 16x16x32 A-layout
#define EXPPV_STEP(MT, SV)                                                 \
  do {                                                                     \
    const float mu = m_i[MT];                                              \
    float ps = 0.f;                                                        \
    s16x4 pf[8];                                                           \
    _Pragma("unroll")                                                      \
    for (int nt = 0; nt < 8; ++nt) {                                       \
      float e0 = exp2f(SV[nt][0] - mu);                                    \
      float e1 = exp2f(SV[nt][1] - mu);                                    \
      float e2 = exp2f(SV[nt][2] - mu);                                    \
      float e3 = exp2f(SV[nt][3] - mu);                                    \
      ps += (e0 + e1) + (e2 + e3);                                         \
      union { u32 w[2]; s16x4 v; } pu;                                     \
      pu.w[0] = pkbf(e0, e1);                                              \
      pu.w[1] = pkbf(e2, e3);                                              \
      pf[nt] = pu.v;                                                       \
    }                                                                      \
    l_i[MT] += ps;                                                         \
    _Pragma("unroll")                                                      \
    for (int nt = 0; nt < 8; ++nt) {                                       \
      union { s16x4 v; u64 ull; } pu2; pu2.v = pf[nt];                     \
      *(u64*)&Ps[(wv * 16 + cc) * 136 + nt * 16 + quad * 4] = pu2.ull;     \
    }                                                                      \
    short8 pa[4];                                                          \
    _Pragma("unroll")                                                      \
    for (int ks = 0; ks < 4; ++ks)                                         \
      pa[ks] = *(const short8*)&Ps[(wv * 16 + cc) * 136 + ks * 32 + quad * 8];\
    _Pragma("unroll")                                                      \
    for (int nt = 0; nt < 4; ++nt) {                                       \
      const int rv = (nt * 16 + cc) * 128;                                 \
      _Pragma("unroll")                                                    \
      for (int ks = 0; ks < 4; ++ks) {                                     \
        const int pos = (ks * 4 + quad + cc) & 15;                         \
        short8 bv = *(const short8*)&Vs[rv + pos * 8];                     \
        o_acc[MT][nt] = __builtin_amdgcn_mfma_f32_16x16x32_bf16(pa[ks], bv, o_acc[MT][nt], 0, 0, 0); \
      }                                                                    \
    }                                                                      \
  } while (0)
#endif

__global__ __launch_bounds__(512, 4) void attn_kernel(const u16* __restrict__ Q,
                                                      const u16* __restrict__ K,
                                                      const u16* __restrict__ Vt,
                                                      u16* __restrict__ O) {
  __shared__ u16 Ks[2][8192];  // double-buffered 128x64 K tiles (32 KB)
  __shared__ u16 Vs[8192];     // 64 d x 128 keys, 16-chunk rotate (16 KB)
#if !HAVE_MFMA16
  __shared__ u16 Ps[8 * 16 * 136];
#endif

  // decode: XCD gets 8 contiguous bh (lin&7 = bh>>3 under lin%8 dispatch).
  const int lin = blockIdx.x;
  const int bh  = (lin & 7) * 8 + ((lin >> 3) & 7);
  const int qt  = lin >> 6;  // 0..7
  const int b = bh >> 4, h = bh & 15;
  const int tid  = threadIdx.x;
  const int lane = tid & 63;
  const int wv   = tid >> 6;   // 0..7
  const int quad = lane >> 4;
  const int cc   = lane & 15;
  const int q0   = qt * 256;

  // Q fragments (B-operand of 16x16x32: B[n=cc][k=quad*8+j]); pre-scaled
  short8 qf[2][2];
#pragma unroll
  for (int mt = 0; mt < 2; mt++) {
    const u16* qp = Q + (size_t)(b * 2048 + q0 + wv * 32 + mt * 16 + cc) * 1024 + h * 64;
    qf[mt][0] = *(const short8*)(qp + quad * 8);
    qf[mt][1] = *(const short8*)(qp + 32 + quad * 8);
  }

  f32x4 o_acc[2][4];
  float m_i[2] = {-3.0e38f, -3.0e38f}, l_i[2] = {0.f, 0.f};
#pragma unroll
  for (int mt = 0; mt < 2; mt++)
#pragma unroll
    for (int nt = 0; nt < 4; nt++) o_acc[mt][nt] = (f32x4){0.f, 0.f, 0.f, 0.f};

  // ---- glds staging addresses (8 waves: 2 K-glds + 2 V-glds each) ----
  // K: wave wv instr j covers rows wv*16 + j*8 + lane/8; chunk pos=lane&7
  //    holds global chunk g = pos ^ (row&7); row&7 == lane>>3.
  const u16* Kp = K + ((size_t)(b * 2048) + wv * 16 + (lane >> 3)) * 1024 + h * 64 +
                  (((lane & 7) ^ (lane >> 3)) * 8);
  // V: wave wv instr j covers rows wv*8 + j*4 + lane/16; pos=lane&15 holds
  //    global chunk g = (pos - row) & 15 (rotate-by-row swizzle).
  const u16* Vp[2];
#pragma unroll
  for (int j = 0; j < 2; j++) {
    int rl = wv * 8 + j * 4 + (lane >> 4);
    int g  = ((lane & 15) - rl) & 15;
    Vp[j] = Vt + ((size_t)(bh * 64) + rl) * 2048 + g * 8;
  }

  const int nkt = 2 * qt + 2;
  const int dt  = 2 * qt + (wv >> 2);     // this wave's diagonal k-tile
  const int pk0 = (quad ^ (cc & 7)) * 8;  // Ks chunk offset for g=quad

  // prologue: stage K[0] into buffer 0 (one-time exposed latency)
#pragma unroll
  for (int j = 0; j < 2; j++)
    glds16(Kp + j * 8192, &Ks[0][wv * 1024 + j * 512]);
  __syncthreads();

  for (int kt = 0; kt < nkt; ++kt) {
    const int cur = kt & 1;

    // issue V[kt] then (if any) K[kt+1] -> drained at the mid barrier,
    // hundreds of cycles of S+mask+max compute after issue
#pragma unroll
    for (int j = 0; j < 2; j++)
      glds16(Vp[j] + kt * 128, Vs + wv * 1024 + j * 512);
    if (kt + 1 < nkt) {
#pragma unroll
      for (int j = 0; j < 2; j++)
        glds16(Kp + (size_t)(kt + 1) * 131072 + j * 8192,
               &Ks[cur ^ 1][wv * 1024 + j * 512]);
    }

    const bool active = (kt <= dt);   // wave-uniform: skip fully-masked tiles
    const bool diag   = (kt == dt);

    f32x4 s[8];
    if (active) {
      S_STEP(0, s);
      if (diag) MASK_STEP(0, s);
      MAXRED_STEP(0, s);
    }

    __syncthreads();  // unconditional: V[kt] (+K[kt+1]) staged -> visible

    if (active) {
      EXPPV_STEP(0, s);
      // ---- mt = 1 ----
      f32x4 t[8];
      S_STEP(1, t);
      if (diag) MASK_STEP(1, t);
      MAXRED_STEP(1, t);
      EXPPV_STEP(1, t);
    }

    __syncthreads();  // unconditional: all waves done with Vs/Ks[cur]
  }

  // epilogue: reduce l across quads, broadcast, normalize, store
#pragma unroll
  for (int mt = 0; mt < 2; ++mt) {
    float l = l_i[mt];
    l += __shfl_xor(l, 16);
    l += __shfl_xor(l, 32);
    const float linv = 1.0f / l;
    f32x4 li4;
#pragma unroll
    for (int r = 0; r < 4; ++r) li4[r] = __shfl(linv, quad * 4 + r);
    const int rowb = b * 2048 + q0 + wv * 32 + mt * 16 + quad * 4;
#pragma unroll
    for (int nt = 0; nt < 4; ++nt)
#pragma unroll
      for (int r = 0; r < 4; ++r)
        O[(size_t)(rowb + r) * 1024 + h * 64 + nt * 16 + cc] = f2b(o_acc[mt][nt][r] * li4[r]);
  }
}

// ---------------- launch ----------------
extern "C" void kernel_launch(void* const* d_in, const int* in_sizes, int n_in,
                              void* d_out, int out_size, void* d_ws, size_t ws_size,
                              hipStream_t stream) {
  const float* x  = (const float*)d_in[0];
  const float* wq = (const float*)d_in[1];
  const float* wk = (const float*)d_in[2];
  const float* wv = (const float*)d_in[3];
  const float* wo = (const float*)d_in[4];
  const int* pos  = (const int*)d_in[5];
  float* out = (float*)d_out;

  char* ws = (char*)d_ws;
  // [0,16M): xb (gemm_qkv A) -> later attn_out   [16M,24M): weights bf16
  // [24M,40M): Q  [40M,56M): K  [56M,72M): Vt (written transposed by gemm)
  u16* xb  = (u16*)(ws);
  u16* aO  = (u16*)(ws);               // overwrites xb after it's dead
  u16* wqb = (u16*)(ws + (16ull << 20));
  u16* wkb = (u16*)(ws + (18ull << 20));
  u16* wvb = (u16*)(ws + (20ull << 20));
  u16* wob = (u16*)(ws + (22ull << 20));
  u16* Qb  = (u16*)(ws + (24ull << 20));
  u16* Kb  = (u16*)(ws + (40ull << 20));
  u16* vt  = (u16*)(ws + (56ull << 20));

  cvt_all<<<12288, 256, 0, stream>>>(x, wq, wk, wv, wo, xb, wqb, wkb, wvb, wob);
  gemm_qkv<<<1536, 256, 0, stream>>>(xb, wqb, wkb, wvb, Qb, Kb, vt, pos);
  attn_kernel<<<512, 512, 0, stream>>>(Qb, Kb, vt, aO);
  gemm_out<<<512, 256, 0, stream>>>(aO, wob, out);
}

// Round 12
// 281.652 us; speedup vs baseline: 1.3447x; 1.3447x over previous
//
#include <hip/hip_runtime.h>
#include <hip/hip_bf16.h>
#include <type_traits>

typedef __attribute__((ext_vector_type(8))) short short8;
typedef __attribute__((ext_vector_type(4))) short s16x4;
typedef __attribute__((ext_vector_type(4))) float f32x4;
typedef unsigned short u16;
typedef unsigned int   u32;
typedef unsigned long long u64;

// B=4, S=2048, D=1024, H=16, DK=64, M = B*S = 8192

#if __has_builtin(__builtin_amdgcn_mfma_f32_16x16x16bf16_1k)
#define MFMA16(a, b, c) __builtin_amdgcn_mfma_f32_16x16x16bf16_1k(a, b, c, 0, 0, 0)
#define HAVE_MFMA16 1
#elif __has_builtin(__builtin_amdgcn_mfma_f32_16x16x16_bf16)
#define MFMA16(a, b, c) __builtin_amdgcn_mfma_f32_16x16x16_bf16(a, b, c, 0, 0, 0)
#define HAVE_MFMA16 1
#else
#define HAVE_MFMA16 0
#endif

static __device__ __forceinline__ u16 f2b(float f) {
  u32 u = __builtin_bit_cast(u32, f);
  u = (u + 0x7fffu + ((u >> 16) & 1u)) >> 16;
  return (u16)u;
}
static __device__ __forceinline__ float b2f(u16 h) {
  return __builtin_bit_cast(float, ((u32)h) << 16);
}
static __device__ __forceinline__ u32 pkbf(float a, float b) {
  // v_cvt_pk_bf16_f32; union pun (bit_cast rejects non-trivially-copyable)
  union { __hip_bfloat162 t; u32 u; } c;
  c.t = __float22bfloat162_rn(make_float2(a, b));
  return c.u;
}

typedef __attribute__((address_space(1))) const unsigned int gas_u32;
typedef __attribute__((address_space(3))) unsigned int las_u32;
static __device__ __forceinline__ void glds16(const u16* g, u16* l) {
  __builtin_amdgcn_global_load_lds((gas_u32*)g, (las_u32*)l, 16, 0, 0);
}

// ---------------- fused fp32 -> bf16 convert (x + 4 weights) ----------------
__global__ __launch_bounds__(256) void cvt_all(
    const float* __restrict__ x, const float* __restrict__ wq,
    const float* __restrict__ wk, const float* __restrict__ wv,
    const float* __restrict__ wo, u16* __restrict__ xb, u16* __restrict__ wqb,
    u16* __restrict__ wkb, u16* __restrict__ wvb, u16* __restrict__ wob) {
  int u = blockIdx.x * 256 + threadIdx.x;  // unit of 4 floats
  if (u >= 3145728) return;
  const float* src; u16* dst; int off;
  if (u < 2097152) { src = x; dst = xb; off = u; }
  else {
    int t = u - 2097152;
    int w = t >> 18;
    off = t & 0x3FFFF;
    src = (w == 0) ? wq : (w == 1) ? wk : (w == 2) ? wv : wo;
    dst = (w == 0) ? wqb : (w == 1) ? wkb : (w == 2) ? wvb : wob;
  }
  int i = off * 4;
  float4 v = *(const float4*)(src + i);
  union { u16 us[4]; u64 ull; } o;
  o.us[0] = f2b(v.x); o.us[1] = f2b(v.y); o.us[2] = f2b(v.z); o.us[3] = f2b(v.w);
  *(u64*)(dst + i) = o.ull;
}

// ---------------- GEMM: C[m,n] = sum_k A[m,k]*B[n,k]  (B^T form) ----------
// TM: 0 = f32 row-major, 2 = bf16 transposed-to-Vt (fused V transpose),
//     3 = bf16 row-major with FUSED RoPE (pairs (2i,2i+1) live in adjacent
//         lanes cc,cc^1 -> one shfl_xor(1) + __sinf/__cosf per element; rsc
//         is the post-rotation scale: Q gets 0.125*log2e, K gets 1.0).
//         NOTE: __sinf/__cosf, NOT sincosf — the pointer-based OCML sincos
//         fails mem2reg in the unrolled epilogue and generated 1.9 GB of
//         scratch writes (R8: gemm_qkv 444us, WRITE_SIZE 1.93GB, VGPR 76).
template <typename OT, int TM>
static __device__ __forceinline__ void gemm_body(const u16* __restrict__ A,
                                                 const u16* __restrict__ B,
                                                 OT* __restrict__ C,
                                                 int m0, int n0,
                                                 const int* __restrict__ pos,
                                                 float rsc) {
  __shared__ u16 As[4096];
  __shared__ u16 Bs[4096];

  const int tid  = threadIdx.x;
  const int lane = tid & 63;
  const int wv   = tid >> 6;
  const int quad = lane >> 4;
  const int cc   = lane & 15;
  const int wr   = wv >> 1;
  const int wc   = wv & 1;

  f32x4 acc[4][4];
#pragma unroll
  for (int i = 0; i < 4; i++)
#pragma unroll
    for (int j = 0; j < 4; j++) acc[i][j] = (f32x4){0.f, 0.f, 0.f, 0.f};

  const int p0 = wv * 128 + lane;
  const int p1 = p0 + 64;
  const int r0 = p0 >> 2, g0 = (p0 & 3) ^ (r0 & 3);
  const int r1 = p1 >> 2, g1 = (p1 & 3) ^ (r1 & 3);
  const u16* gA0 = A + (size_t)(m0 + r0) * 1024 + g0 * 8;
  const u16* gA1 = A + (size_t)(m0 + r1) * 1024 + g1 * 8;
  const u16* gB0 = B + (size_t)(n0 + r0) * 1024 + g0 * 8;
  const u16* gB1 = B + (size_t)(n0 + r1) * 1024 + g1 * 8;
  u16* lA = As + wv * 1024;
  u16* lB = Bs + wv * 1024;

  for (int k0 = 0; k0 < 1024; k0 += 32) {
    __syncthreads();
    glds16(gA0 + k0, lA);
    glds16(gA1 + k0, lA + 512);
    glds16(gB0 + k0, lB);
    glds16(gB1 + k0, lB + 512);
    __syncthreads();

    short8 af[4], bf[4];
#pragma unroll
    for (int mt = 0; mt < 4; mt++) {
      int ra = wr * 64 + mt * 16 + cc;
      af[mt] = *(const short8*)&As[ra * 32 + ((quad ^ (ra & 3)) * 8)];
    }
#pragma unroll
    for (int nt = 0; nt < 4; nt++) {
      int rb = wc * 64 + nt * 16 + cc;
      bf[nt] = *(const short8*)&Bs[rb * 32 + ((quad ^ (rb & 3)) * 8)];
    }
#pragma unroll
    for (int mt = 0; mt < 4; mt++)
#pragma unroll
      for (int nt = 0; nt < 4; nt++)
        acc[mt][nt] = __builtin_amdgcn_mfma_f32_16x16x32_bf16(af[mt], bf[nt], acc[mt][nt], 0, 0, 0);
  }

  if constexpr (TM == 3) {
    // fused RoPE epilogue (scratch-free trig)
    float prow[4][4];  // token position per (mt, r)
#pragma unroll
    for (int mt = 0; mt < 4; mt++)
#pragma unroll
      for (int r = 0; r < 4; r++)
        prow[mt][r] = (float)pos[(m0 + wr * 64 + mt * 16 + quad * 4 + r) & 2047];
#pragma unroll
    for (int mt = 0; mt < 4; mt++)
#pragma unroll
      for (int nt = 0; nt < 4; nt++) {
        const int col = n0 + wc * 64 + nt * 16 + cc;
        const int fi  = (col & 63) >> 1;
        const float inv = exp2f(-(float)fi * 0.41524101186092033f);
        const bool odd = col & 1;
#pragma unroll
        for (int r = 0; r < 4; r++) {
          const int row = m0 + wr * 64 + mt * 16 + quad * 4 + r;
          const float ang = prow[mt][r] * inv;
          const float sn = __sinf(ang);
          const float cs = __cosf(ang);
          const float x = acc[mt][nt][r];
          const float p = __shfl_xor(x, 1);
          const float y = odd ? (p * sn + x * cs) : (x * cs - p * sn);
          C[(size_t)row * 1024 + col] = f2b(y * rsc);
        }
      }
  } else {
#pragma unroll
    for (int mt = 0; mt < 4; mt++)
#pragma unroll
      for (int nt = 0; nt < 4; nt++) {
        if constexpr (TM == 2) {
          const int col = n0 + wc * 64 + nt * 16 + cc;
          const int rowbase = m0 + wr * 64 + mt * 16 + quad * 4;
          const int bsel = rowbase >> 11;
          const int s0 = rowbase & 2047;
          union { u16 us[4]; u64 ull; } o;
#pragma unroll
          for (int r = 0; r < 4; r++) o.us[r] = f2b(acc[mt][nt][r]);
          *(u64*)&C[((size_t)(bsel * 1024 + col)) * 2048 + s0] = o.ull;
        } else {
#pragma unroll
          for (int r = 0; r < 4; r++) {
            int row = m0 + wr * 64 + mt * 16 + quad * 4 + r;
            int col = n0 + wc * 64 + nt * 16 + cc;
            C[(size_t)row * 1024 + col] = acc[mt][nt][r];
          }
        }
      }
  }
}

// linear grid 1536, XCD-swizzled: each XCD gets 8 contiguous m-panels with
// all their (sel, n0) blocks -> A-panel reuse stays in one XCD's L2.
__global__ __launch_bounds__(256) void gemm_qkv(const u16* __restrict__ A,
                                                const u16* __restrict__ Bq,
                                                const u16* __restrict__ Bk,
                                                const u16* __restrict__ Bv,
                                                u16* __restrict__ Q,
                                                u16* __restrict__ K,
                                                u16* __restrict__ Vt,
                                                const int* __restrict__ pos) {
  const int lin = blockIdx.x;
  const int swz = (lin & 7) * 192 + (lin >> 3);
  const int m0  = (swz / 24) * 128;
  const int rem = swz % 24;
  const int sel = rem >> 3;
  const int n0  = (rem & 7) * 128;
  if (sel == 0)      gemm_body<u16, 3>(A, Bq, Q,  m0, n0, pos, 0.18033688011112042f);
  else if (sel == 1) gemm_body<u16, 3>(A, Bk, K,  m0, n0, pos, 1.0f);
  else               gemm_body<u16, 2>(A, Bv, Vt, m0, n0, nullptr, 0.f);
}

__global__ __launch_bounds__(256) void gemm_out(const u16* __restrict__ A,
                                                const u16* __restrict__ B,
                                                float* __restrict__ C) {
  const int lin = blockIdx.x;
  const int swz = (lin & 7) * 64 + (lin >> 3);
  gemm_body<float, 0>(A, B, C, (swz >> 3) * 128, (swz & 7) * 128, nullptr, 0.f);
}

// ---------------- causal flash attention V9 (verbatim from R9: 93.2us) ----
// Final configuration. Occupancy experiments beyond this (q-tile pairing R1,
// 8-wave QBLK=256 R10, 5-block TLP R11) all lost: the per-wave state (~150
// unified regs) fits exactly 3 waves/SIMD; any forced-occupancy config
// spills to scratch (R10: 294MB spill, 2x slower).

#define S_STEP(MT, SV)                                                     \
  do {                                                                     \
    __builtin_amdgcn_s_setprio(1);                                         \
    _Pragma("unroll")                                                      \
    for (int nt = 0; nt < 8; ++nt) {                                       \
      const int rbase = (nt * 16 + cc) * 64;                               \
      short8 bk0 = *(const short8*)&Ks[cur][rbase + pk0];                  \
      short8 bk1 = *(const short8*)&Ks[cur][rbase + (pk0 ^ 32)];           \
      f32x4 z = (f32x4){0.f, 0.f, 0.f, 0.f};                               \
      z = __builtin_amdgcn_mfma_f32_16x16x32_bf16(bk0, qf[MT][0], z, 0, 0, 0); \
      SV[nt] = __builtin_amdgcn_mfma_f32_16x16x32_bf16(bk1, qf[MT][1], z, 0, 0, 0); \
    }                                                                      \
    __builtin_amdgcn_s_setprio(0);                                         \
  } while (0)

#define MASK_STEP(MT, SV)                                                  \
  do {                                                                     \
    const int qg = q0 + wv * 32 + MT * 16 + cc;                            \
    const int kb = kt * 128 + quad * 4;                                    \
    _Pragma("unroll")                                                      \
    for (int nt = 0; nt < 8; ++nt)                                         \
      _Pragma("unroll")                                                    \
      for (int r = 0; r < 4; ++r)                                          \
        if (kb + nt * 16 + r > qg) SV[nt][r] = -3.0e38f;                   \
  } while (0)

// max-reduce + deferred rescale (T13): skip o_acc rescale while the new
// tile max stays within 2^11 of the running max.
#define MAXRED_STEP(MT, SV)                                                \
  do {                                                                     \
    float mx = fmaxf(fmaxf(SV[0][0], SV[0][1]), fmaxf(SV[0][2], SV[0][3]));\
    _Pragma("unroll")                                                      \
    for (int nt = 1; nt < 8; ++nt)                                         \
      mx = fmaxf(mx, fmaxf(fmaxf(SV[nt][0], SV[nt][1]),                    \
                           fmaxf(SV[nt][2], SV[nt][3])));                  \
    mx = fmaxf(mx, __shfl_xor(mx, 16));                                    \
    mx = fmaxf(mx, __shfl_xor(mx, 32));                                    \
    if (!__all(mx <= m_i[MT] + 11.0f)) {                                   \
      const float mn = fmaxf(m_i[MT], mx);                                 \
      const float al = exp2f(m_i[MT] - mn);                                \
      m_i[MT] = mn;                                                        \
      l_i[MT] *= al;                                                       \
      f32x4 al4;                                                           \
      _Pragma("unroll")                                                    \
      for (int r = 0; r < 4; ++r) al4[r] = __shfl(al, quad * 4 + r);       \
      _Pragma("unroll")                                                    \
      for (int nt = 0; nt < 4; ++nt) o_acc[MT][nt] *= al4;                 \
    }                                                                      \
  } while (0)

#if HAVE_MFMA16
// fused exp2 -> pack -> PV, kk-outer: one P fragment live at a time
#define EXPPV_STEP(MT, SV)                                                 \
  do {                                                                     \
    const float mu = m_i[MT];                                              \
    float ps = 0.f;                                                        \
    __builtin_amdgcn_s_setprio(1);                                         \
    _Pragma("unroll")                                                      \
    for (int kk = 0; kk < 8; ++kk) {                                       \
      float e0 = exp2f(SV[kk][0] - mu);                                    \
      float e1 = exp2f(SV[kk][1] - mu);                                    \
      float e2 = exp2f(SV[kk][2] - mu);                                    \
      float e3 = exp2f(SV[kk][3] - mu);                                    \
      ps += (e0 + e1) + (e2 + e3);                                         \
      union { u32 w[2]; s16x4 v; } pu;                                     \
      pu.w[0] = pkbf(e0, e1);                                              \
      pu.w[1] = pkbf(e2, e3);                                              \
      const int pos = (kk * 2 + (quad >> 1) + cc) & 15;                    \
      _Pragma("unroll")                                                    \
      for (int nt = 0; nt < 4; ++nt) {                                     \
        s16x4 bv = *(const s16x4*)&Vs[(nt * 16 + cc) * 128 + pos * 8 + (quad & 1) * 4]; \
        o_acc[MT][nt] = MFMA16(pu.v, bv, o_acc[MT][nt]);                   \
      }                                                                    \
    }                                                                      \
    __builtin_amdgcn_s_setprio(0);                                         \
    l_i[MT] += ps;                                                         \
  } while (0)
#else
// fallback: exp all, stage P through LDS to 16x16x32 A-layout
#define EXPPV_STEP(MT, SV)                                                 \
  do {                                                                     \
    const float mu = m_i[MT];                                              \
    float ps = 0.f;                                                        \
    s16x4 pf[8];                                                           \
    _Pragma("unroll")                                                      \
    for (int nt = 0; nt < 8; ++nt) {                                       \
      float e0 = exp2f(SV[nt][0] - mu);                                    \
      float e1 = exp2f(SV[nt][1] - mu);                                    \
      float e2 = exp2f(SV[nt][2] - mu);                                    \
      float e3 = exp2f(SV[nt][3] - mu);                                    \
      ps += (e0 + e1) + (e2 + e3);                                         \
      union { u32 w[2]; s16x4 v; } pu;                                     \
      pu.w[0] = pkbf(e0, e1);                                              \
      pu.w[1] = pkbf(e2, e3);                                              \
      pf[nt] = pu.v;                                                       \
    }                                                                      \
    l_i[MT] += ps;                                                         \
    _Pragma("unroll")                                                      \
    for (int nt = 0; nt < 8; ++nt) {                                       \
      union { s16x4 v; u64 ull; } pu2; pu2.v = pf[nt];                     \
      *(u64*)&Ps[(wv * 16 + cc) * 136 + nt * 16 + quad * 4] = pu2.ull;     \
    }                                                                      \
    short8 pa[4];                                                          \
    _Pragma("unroll")                                                      \
    for (int ks = 0; ks < 4; ++ks)                                         \
      pa[ks] = *(const short8*)&Ps[(wv * 16 + cc) * 136 + ks * 32 + quad * 8];\
    _Pragma("unroll")                                                      \
    for (int nt = 0; nt < 4; ++nt) {                                       \
      const int rv = (nt * 16 + cc) * 128;                                 \
      _Pragma("unroll")                                                    \
      for (int ks = 0; ks < 4; ++ks) {                                     \
        const int pos = (ks * 4 + quad + cc) & 15;                         \
        short8 bv = *(const short8*)&Vs[rv + pos * 8];                     \
        o_acc[MT][nt] = __builtin_amdgcn_mfma_f32_16x16x32_bf16(pa[ks], bv, o_acc[MT][nt], 0, 0, 0); \
      }                                                                    \
    }                                                                      \
  } while (0)
#endif

__global__ __launch_bounds__(256, 3) void attn_kernel(const u16* __restrict__ Q,
                                                      const u16* __restrict__ K,
                                                      const u16* __restrict__ Vt,
                                                      u16* __restrict__ O) {
  __shared__ u16 Ks[2][8192];  // double-buffered 128x64 K tiles (32 KB)
  __shared__ u16 Vs[8192];     // 64 d x 128 keys, 16-chunk rotate (16 KB)
#if !HAVE_MFMA16
  __shared__ u16 Ps[4 * 16 * 136];
#endif

  const int bh = blockIdx.x;
  const int qt = 15 - blockIdx.y;  // heavy-first LPT
  const int b = bh >> 4, h = bh & 15;
  const int tid  = threadIdx.x;
  const int lane = tid & 63;
  const int wv   = tid >> 6;
  const int quad = lane >> 4;
  const int cc   = lane & 15;
  const int q0   = qt * 128;

  // Q fragments (B-operand of 16x16x32: B[n=cc][k=quad*8+j]); pre-scaled
  short8 qf[2][2];
#pragma unroll
  for (int mt = 0; mt < 2; mt++) {
    const u16* qp = Q + (size_t)(b * 2048 + q0 + wv * 32 + mt * 16 + cc) * 1024 + h * 64;
    qf[mt][0] = *(const short8*)(qp + quad * 8);
    qf[mt][1] = *(const short8*)(qp + 32 + quad * 8);
  }

  f32x4 o_acc[2][4];
  float m_i[2] = {-3.0e38f, -3.0e38f}, l_i[2] = {0.f, 0.f};
#pragma unroll
  for (int mt = 0; mt < 2; mt++)
#pragma unroll
    for (int nt = 0; nt < 4; nt++) o_acc[mt][nt] = (f32x4){0.f, 0.f, 0.f, 0.f};

  // ---- glds staging addresses ----
  // K: wave wv, instr j covers rows wv*32+j*8 + lane/8; chunk pos=lane&7
  //    holds global chunk g = pos ^ (row&7); row&7 == lane>>3.
  const u16* Kp = K + ((size_t)(b * 2048) + wv * 32 + (lane >> 3)) * 1024 + h * 64 +
                  (((lane & 7) ^ (lane >> 3)) * 8);
  // V: wave wv, instr j covers rows wv*16+j*4 + lane/16; pos=lane&15 holds
  //    global chunk g = (pos - row) & 15  (rotate-by-row swizzle).
  const u16* Vp[4];
#pragma unroll
  for (int j = 0; j < 4; j++) {
    int rl = wv * 16 + j * 4 + (lane >> 4);
    int g  = ((lane & 15) - rl) & 15;
    Vp[j] = Vt + ((size_t)(bh * 64) + rl) * 2048 + g * 8;
  }

  const int nkt = qt + 1;
  const int pk0 = (quad ^ (cc & 7)) * 8;  // Ks chunk offset for g=quad

  // prologue: stage K[0] into buffer 0 (one-time exposed latency)
#pragma unroll
  for (int j = 0; j < 4; j++)
    glds16(Kp + j * 8192, &Ks[0][wv * 2048 + j * 512]);
  __syncthreads();

  for (int kt = 0; kt < nkt; ++kt) {
    const int cur = kt & 1;

    // issue V[kt] then (if any) K[kt+1] -> drained at the mid barrier,
    // ~500 cycles of S(mt0)+mask+max compute after issue
#pragma unroll
    for (int j = 0; j < 4; j++)
      glds16(Vp[j] + kt * 128, Vs + wv * 2048 + j * 512);
    if (kt + 1 < nkt) {
#pragma unroll
      for (int j = 0; j < 4; j++)
        glds16(Kp + (size_t)(kt + 1) * 131072 + j * 8192,
               &Ks[cur ^ 1][wv * 2048 + j * 512]);
    }

    const bool diag = (kt == qt);

    // ---- mt = 0 ----
    {
      f32x4 s[8];
      S_STEP(0, s);
      if (diag) MASK_STEP(0, s);
      MAXRED_STEP(0, s);

      __syncthreads();  // V[kt] (+K[kt+1]) staged -> visible

      EXPPV_STEP(0, s);
    }

    // ---- mt = 1 ----
    {
      f32x4 s[8];
      S_STEP(1, s);
      if (diag) MASK_STEP(1, s);
      MAXRED_STEP(1, s);
      EXPPV_STEP(1, s);
    }

    __syncthreads();  // all waves done with Vs/Ks[cur] before restage
  }

  // epilogue: reduce l across quads, broadcast, normalize, store
#pragma unroll
  for (int mt = 0; mt < 2; ++mt) {
    float l = l_i[mt];
    l += __shfl_xor(l, 16);
    l += __shfl_xor(l, 32);
    const float linv = 1.0f / l;
    f32x4 li4;
#pragma unroll
    for (int r = 0; r < 4; ++r) li4[r] = __shfl(linv, quad * 4 + r);
    const int rowb = b * 2048 + q0 + wv * 32 + mt * 16 + quad * 4;
#pragma unroll
    for (int nt = 0; nt < 4; ++nt)
#pragma unroll
      for (int r = 0; r < 4; ++r)
        O[(size_t)(rowb + r) * 1024 + h * 64 + nt * 16 + cc] = f2b(o_acc[mt][nt][r] * li4[r]);
  }
}

// ---------------- launch ----------------
extern "C" void kernel_launch(void* const* d_in, const int* in_sizes, int n_in,
                              void* d_out, int out_size, void* d_ws, size_t ws_size,
                              hipStream_t stream) {
  const float* x  = (const float*)d_in[0];
  const float* wq = (const float*)d_in[1];
  const float* wk = (const float*)d_in[2];
  const float* wv = (const float*)d_in[3];
  const float* wo = (const float*)d_in[4];
  const int* pos  = (const int*)d_in[5];
  float* out = (float*)d_out;

  char* ws = (char*)d_ws;
  // [0,16M): xb (gemm_qkv A) -> later attn_out   [16M,24M): weights bf16
  // [24M,40M): Q  [40M,56M): K  [56M,72M): Vt (written transposed by gemm)
  u16* xb  = (u16*)(ws);
  u16* aO  = (u16*)(ws);               // overwrites xb after it's dead
  u16* wqb = (u16*)(ws + (16ull << 20));
  u16* wkb = (u16*)(ws + (18ull << 20));
  u16* wvb = (u16*)(ws + (20ull << 20));
  u16* wob = (u16*)(ws + (22ull << 20));
  u16* Qb  = (u16*)(ws + (24ull << 20));
  u16* Kb  = (u16*)(ws + (40ull << 20));
  u16* vt  = (u16*)(ws + (56ull << 20));

  cvt_all<<<12288, 256, 0, stream>>>(x, wq, wk, wv, wo, xb, wqb, wkb, wvb, wob);
  gemm_qkv<<<1536, 256, 0, stream>>>(xb, wqb, wkb, wvb, Qb, Kb, vt, pos);
  attn_kernel<<<dim3(64, 16), 256, 0, stream>>>(Qb, Kb, vt, aO);
  gemm_out<<<512, 256, 0, stream>>>(aO, wob, out);
}